// Round 2
// baseline (176.172 us; speedup 1.0000x reference)
//
#include <hip/hip_runtime.h>
#include <hip/hip_bf16.h>
#include <math.h>

#define DIM 1024
#define HEADS 16
#define HEAD_DIM 64
#define MAXSEQ 4096
#define BATCH 16
#define CHUNK 64
#define NCHUNK (MAXSEQ / CHUNK)  // 64

// ---------------- Kernel A: QKV projection ----------------
__global__ __launch_bounds__(256) void qkv_proj(
    const float* __restrict__ token,
    const float* __restrict__ Wq, const float* __restrict__ Wk,
    const float* __restrict__ Wv,
    float* __restrict__ out /* 3 x 16 x 1024 */) {
  __shared__ float tok[BATCH * DIM];  // 64 KiB
  for (int idx = threadIdx.x; idx < BATCH * DIM; idx += 256)
    tok[idx] = token[idx];
  __syncthreads();

  const float* W = (blockIdx.y == 0) ? Wq : ((blockIdx.y == 1) ? Wk : Wv);
  float* o = out + (size_t)blockIdx.y * BATCH * DIM;

  const int wave = threadIdx.x >> 6;
  const int lane = threadIdx.x & 63;
  const int i0 = blockIdx.x * 16 + wave * 4;

  float acc[4][16];
#pragma unroll
  for (int ii = 0; ii < 4; ++ii)
#pragma unroll
    for (int b = 0; b < 16; ++b) acc[ii][b] = 0.f;

  for (int t = 0; t < 16; ++t) {
    const int j = t * 64 + lane;
    float tk[16];
#pragma unroll
    for (int b = 0; b < 16; ++b) tk[b] = tok[b * DIM + j];
#pragma unroll
    for (int ii = 0; ii < 4; ++ii) {
      const float w = W[(size_t)(i0 + ii) * DIM + j];
#pragma unroll
      for (int b = 0; b < 16; ++b) acc[ii][b] = fmaf(w, tk[b], acc[ii][b]);
    }
  }

#pragma unroll
  for (int ii = 0; ii < 4; ++ii)
#pragma unroll
    for (int b = 0; b < 16; ++b) {
      float v = acc[ii][b];
#pragma unroll
      for (int m = 32; m >= 1; m >>= 1) v += __shfl_xor(v, m);
      if (lane == 0) o[(size_t)b * DIM + i0 + ii] = v;
    }
}

// ---------------- Kernel B: flash-decode attention partials ----------------
// grid (NCHUNK, BATCH), block 256. Block owns ALL 16 heads for one batch and
// a CHUNK of seq positions. Every K/V row access = one contiguous 4KB load.
// Thread t: head h = t>>4, dims (t&15)*4 .. +4.
// partial layout per (b,h,c): [m, l, acc[64]]  (66 floats)
__global__ __launch_bounds__(256) void attn_partial(
    const float* __restrict__ kc, const float* __restrict__ vc,
    const float* __restrict__ qkv, const int* __restrict__ pos_p,
    float* __restrict__ part) {
  const int c = blockIdx.x, b = blockIdx.y;
  const int t = threadIdx.x;
  const int h = t >> 4, lq = t & 15;
  const int pos = pos_p[0];
  const int nk = pos + 1;
  const int s0 = c * CHUNK;

  const float* qp   = qkv + (size_t)b * DIM;
  const float* knew = qkv + (size_t)BATCH * DIM + (size_t)b * DIM;
  const float* vnew = qkv + 2 * (size_t)BATCH * DIM + (size_t)b * DIM;
  const float* kbase = kc + (size_t)b * MAXSEQ * DIM;
  const float* vbase = vc + (size_t)b * MAXSEQ * DIM;

  const float scale = 0.125f;  // 1/sqrt(64)
  float4 q4 = *(const float4*)(qp + 4 * t);
  q4.x *= scale; q4.y *= scale; q4.z *= scale; q4.w *= scale;

  __shared__ float sc[CHUNK][17];  // padded: softmax reads conflict-free

  // ---- phase 1: scores (streaming K, fully coalesced) ----
#pragma unroll 4
  for (int i = 0; i < CHUNK; ++i) {
    const int s = s0 + i;
    const bool valid = (s < nk);
    float d = 0.f;
    if (valid) {
      const float* krow = (s == pos) ? knew : (kbase + (size_t)s * DIM);
      const float4 k4 = *(const float4*)(krow + 4 * t);
      d = q4.x * k4.x + q4.y * k4.y + q4.z * k4.z + q4.w * k4.w;
      d += __shfl_xor(d, 1);
      d += __shfl_xor(d, 2);
      d += __shfl_xor(d, 4);
      d += __shfl_xor(d, 8);
    }
    if (lq == 0) sc[i][h] = valid ? d : -INFINITY;
  }
  __syncthreads();

  // ---- phase 2: per-head softmax over CHUNK scores ----
  // 16-thread group per head; each thread handles CHUNK/16 = 4 entries.
  float m = -INFINITY;
#pragma unroll
  for (int r = 0; r < CHUNK / 16; ++r)
    m = fmaxf(m, sc[lq * (CHUNK / 16) + r][h]);
  m = fmaxf(m, __shfl_xor(m, 1));
  m = fmaxf(m, __shfl_xor(m, 2));
  m = fmaxf(m, __shfl_xor(m, 4));
  m = fmaxf(m, __shfl_xor(m, 8));

  float l = 0.f;
#pragma unroll
  for (int r = 0; r < CHUNK / 16; ++r) {
    const int i = lq * (CHUNK / 16) + r;
    const float sv = sc[i][h];
    const float p = (sv == -INFINITY) ? 0.f : __expf(sv - m);
    l += p;
    sc[i][h] = p;
  }
  l += __shfl_xor(l, 1);
  l += __shfl_xor(l, 2);
  l += __shfl_xor(l, 4);
  l += __shfl_xor(l, 8);
  __syncthreads();

  // ---- phase 3: V accumulate (streaming V, fully coalesced) ----
  float4 a4 = make_float4(0.f, 0.f, 0.f, 0.f);
#pragma unroll 4
  for (int i = 0; i < CHUNK; ++i) {
    const int s = s0 + i;
    if (s < nk) {
      const float* vrow = (s == pos) ? vnew : (vbase + (size_t)s * DIM);
      const float4 v4 = *(const float4*)(vrow + 4 * t);
      const float p = sc[i][h];  // broadcast within 16-lane group
      a4.x = fmaf(p, v4.x, a4.x);
      a4.y = fmaf(p, v4.y, a4.y);
      a4.z = fmaf(p, v4.z, a4.z);
      a4.w = fmaf(p, v4.w, a4.w);
    }
  }

  const size_t base = (((size_t)(b * HEADS + h)) * NCHUNK + c) * 66;
  part[base + 2 + lq * 4 + 0] = a4.x;
  part[base + 2 + lq * 4 + 1] = a4.y;
  part[base + 2 + lq * 4 + 2] = a4.z;
  part[base + 2 + lq * 4 + 3] = a4.w;
  if (lq == 0) { part[base] = m; part[base + 1] = l; }
}

// ---------------- Kernel C: combine partials ----------------
__global__ __launch_bounds__(64) void attn_combine(
    const float* __restrict__ part, float* __restrict__ attn) {
  const int bh = blockIdx.x;
  const int b = bh >> 4, h = bh & 15;
  const int d = threadIdx.x;
  const float* p0 = part + (size_t)bh * NCHUNK * 66;
  float M = -INFINITY;
#pragma unroll
  for (int c = 0; c < NCHUNK; ++c) M = fmaxf(M, p0[c * 66]);
  float L = 0.f, o = 0.f;
#pragma unroll 8
  for (int c = 0; c < NCHUNK; ++c) {
    const float mc = p0[c * 66];
    if (mc > -INFINITY) {
      const float w = __expf(mc - M);
      L += p0[c * 66 + 1] * w;
      o = fmaf(p0[c * 66 + 2 + d], w, o);
    }
  }
  attn[(size_t)b * DIM + h * HEAD_DIM + d] = o / L;
}

// ---------------- Kernel D: output projection ----------------
__global__ __launch_bounds__(256) void o_proj(
    const float* __restrict__ attn, const float* __restrict__ Wo,
    float* __restrict__ out) {
  __shared__ float tok[BATCH * DIM];
  for (int idx = threadIdx.x; idx < BATCH * DIM; idx += 256)
    tok[idx] = attn[idx];
  __syncthreads();

  const int wave = threadIdx.x >> 6;
  const int lane = threadIdx.x & 63;
  const int i0 = blockIdx.x * 16 + wave * 4;

  float acc[4][16];
#pragma unroll
  for (int ii = 0; ii < 4; ++ii)
#pragma unroll
    for (int b = 0; b < 16; ++b) acc[ii][b] = 0.f;

  for (int t = 0; t < 16; ++t) {
    const int j = t * 64 + lane;
    float tk[16];
#pragma unroll
    for (int b = 0; b < 16; ++b) tk[b] = tok[b * DIM + j];
#pragma unroll
    for (int ii = 0; ii < 4; ++ii) {
      const float w = Wo[(size_t)(i0 + ii) * DIM + j];
#pragma unroll
      for (int b = 0; b < 16; ++b) acc[ii][b] = fmaf(w, tk[b], acc[ii][b]);
    }
  }

#pragma unroll
  for (int ii = 0; ii < 4; ++ii)
#pragma unroll
    for (int b = 0; b < 16; ++b) {
      float v = acc[ii][b];
#pragma unroll
      for (int m = 32; m >= 1; m >>= 1) v += __shfl_xor(v, m);
      if (lane == 0) out[(size_t)b * DIM + i0 + ii] = v;
    }
}

extern "C" void kernel_launch(void* const* d_in, const int* in_sizes, int n_in,
                              void* d_out, int out_size, void* d_ws, size_t ws_size,
                              hipStream_t stream) {
  const float* token = (const float*)d_in[0];
  const float* kc = (const float*)d_in[1];
  const float* vc = (const float*)d_in[2];
  const float* Wq = (const float*)d_in[3];
  const float* Wk = (const float*)d_in[4];
  const float* Wv = (const float*)d_in[5];
  const float* Wo = (const float*)d_in[6];
  const int* pos = (const int*)d_in[7];
  float* out = (float*)d_out;
  float* ws = (float*)d_ws;

  // workspace layout (floats):
  //  [0, 49152)   : q,k,v projections (3 x 16 x 1024)
  //  then         : attention partials 16*16*NCHUNK*66
  //  then         : combined attention output 16 x 1024
  float* qkv = ws;
  float* part = ws + 3 * BATCH * DIM;
  float* attn = part + (size_t)BATCH * HEADS * NCHUNK * 66;

  hipLaunchKernelGGL(qkv_proj, dim3(64, 3), dim3(256), 0, stream,
                     token, Wq, Wk, Wv, qkv);
  hipLaunchKernelGGL(attn_partial, dim3(NCHUNK, BATCH), dim3(256), 0,
                     stream, kc, vc, qkv, pos, part);
  hipLaunchKernelGGL(attn_combine, dim3(BATCH * HEADS), dim3(64), 0, stream,
                     part, attn);
  hipLaunchKernelGGL(o_proj, dim3(64), dim3(256), 0, stream, attn, Wo, out);
  (void)in_sizes; (void)n_in; (void)out_size; (void)ws_size;
}

// Round 3
// 167.171 us; speedup vs baseline: 1.0538x; 1.0538x over previous
//
#include <hip/hip_runtime.h>
#include <hip/hip_bf16.h>
#include <math.h>

#define DIM 1024
#define HEADS 16
#define HEAD_DIM 64
#define MAXSEQ 4096
#define BATCH 16
#define CHUNK 64
#define NCHUNK (MAXSEQ / CHUNK)  // 64
#define TILE 8

// ---------------- Kernel A: QKV projection ----------------
__global__ __launch_bounds__(256) void qkv_proj(
    const float* __restrict__ token,
    const float* __restrict__ Wq, const float* __restrict__ Wk,
    const float* __restrict__ Wv,
    float* __restrict__ out /* 3 x 16 x 1024 */) {
  __shared__ float tok[BATCH * DIM];  // 64 KiB
  for (int idx = threadIdx.x; idx < BATCH * DIM; idx += 256)
    tok[idx] = token[idx];
  __syncthreads();

  const float* W = (blockIdx.y == 0) ? Wq : ((blockIdx.y == 1) ? Wk : Wv);
  float* o = out + (size_t)blockIdx.y * BATCH * DIM;

  const int wave = threadIdx.x >> 6;
  const int lane = threadIdx.x & 63;
  const int i0 = blockIdx.x * 16 + wave * 4;

  float acc[4][16];
#pragma unroll
  for (int ii = 0; ii < 4; ++ii)
#pragma unroll
    for (int b = 0; b < 16; ++b) acc[ii][b] = 0.f;

  for (int t = 0; t < 16; ++t) {
    const int j = t * 64 + lane;
    float tk[16];
#pragma unroll
    for (int b = 0; b < 16; ++b) tk[b] = tok[b * DIM + j];
#pragma unroll
    for (int ii = 0; ii < 4; ++ii) {
      const float w = W[(size_t)(i0 + ii) * DIM + j];
#pragma unroll
      for (int b = 0; b < 16; ++b) acc[ii][b] = fmaf(w, tk[b], acc[ii][b]);
    }
  }

#pragma unroll
  for (int ii = 0; ii < 4; ++ii)
#pragma unroll
    for (int b = 0; b < 16; ++b) {
      float v = acc[ii][b];
#pragma unroll
      for (int m = 32; m >= 1; m >>= 1) v += __shfl_xor(v, m);
      if (lane == 0) o[(size_t)b * DIM + i0 + ii] = v;
    }
}

// ---------------- Kernel B: single-pass flash-decode partials ----------------
// grid (NCHUNK, BATCH), block 256. Block covers ALL 16 heads of one batch for
// CHUNK seq positions. Thread t: head t>>4, dims (t&15)*4..+4.
// No LDS, no __syncthreads — online softmax per 16-lane head group.
// Per tile of 8 positions: 16 independent float4 loads (K+V) in flight,
// 8 interleaved shfl-reduce chains, ONE rescale of the accumulator.
// partial layout per (b,h,c): [m, l, acc[64]]  (66 floats)
__global__ __launch_bounds__(256) void attn_partial(
    const float* __restrict__ kc, const float* __restrict__ vc,
    const float* __restrict__ qkv, const int* __restrict__ pos_p,
    float* __restrict__ part) {
  const int c = blockIdx.x, b = blockIdx.y;
  const int t = threadIdx.x;
  const int h = t >> 4, lq = t & 15;
  const int pos = pos_p[0];
  const int nk = pos + 1;
  const int s0 = c * CHUNK;

  const float* qp   = qkv + (size_t)b * DIM;
  const float* knew = qkv + (size_t)BATCH * DIM + (size_t)b * DIM;
  const float* vnew = qkv + 2 * (size_t)BATCH * DIM + (size_t)b * DIM;
  const float* kbase = kc + (size_t)b * MAXSEQ * DIM;
  const float* vbase = vc + (size_t)b * MAXSEQ * DIM;

  const float scale = 0.125f;  // 1/sqrt(64)
  float4 q4 = *(const float4*)(qp + 4 * t);
  q4.x *= scale; q4.y *= scale; q4.z *= scale; q4.w *= scale;

  float m = -INFINITY, l = 0.f;
  float4 a4 = make_float4(0.f, 0.f, 0.f, 0.f);

  for (int i0 = 0; i0 < CHUNK; i0 += TILE) {
    // ---- issue all K and V loads for the tile (independent, in flight) ----
    float4 k4[TILE], v4[TILE];
#pragma unroll
    for (int j = 0; j < TILE; ++j) {
      const int s = s0 + i0 + j;
      // loads are always in-bounds (s < MAXSEQ); invalid rows masked later
      const float* krow = (s == pos) ? knew : (kbase + (size_t)s * DIM);
      const float* vrow = (s == pos) ? vnew : (vbase + (size_t)s * DIM);
      k4[j] = *(const float4*)(krow + 4 * t);
      v4[j] = *(const float4*)(vrow + 4 * t);
    }

    // ---- partial dots ----
    float sc[TILE];
#pragma unroll
    for (int j = 0; j < TILE; ++j)
      sc[j] = q4.x * k4[j].x + q4.y * k4[j].y + q4.z * k4[j].z +
              q4.w * k4[j].w;

    // ---- 8 independent 4-deep shfl reduce chains (ILP) ----
#pragma unroll
    for (int j = 0; j < TILE; ++j) {
      sc[j] += __shfl_xor(sc[j], 1);
      sc[j] += __shfl_xor(sc[j], 2);
      sc[j] += __shfl_xor(sc[j], 4);
      sc[j] += __shfl_xor(sc[j], 8);
    }
#pragma unroll
    for (int j = 0; j < TILE; ++j)
      if (s0 + i0 + j >= nk) sc[j] = -INFINITY;

    // ---- online softmax update (one rescale per tile) ----
    float tm = sc[0];
#pragma unroll
    for (int j = 1; j < TILE; ++j) tm = fmaxf(tm, sc[j]);
    const float m_new = fmaxf(m, tm);
    const float corr = (m_new == -INFINITY) ? 1.f : __expf(m - m_new);
    l *= corr;
    a4.x *= corr; a4.y *= corr; a4.z *= corr; a4.w *= corr;
    m = m_new;

#pragma unroll
    for (int j = 0; j < TILE; ++j) {
      const float p = (sc[j] == -INFINITY) ? 0.f : __expf(sc[j] - m);
      l += p;
      a4.x = fmaf(p, v4[j].x, a4.x);
      a4.y = fmaf(p, v4[j].y, a4.y);
      a4.z = fmaf(p, v4[j].z, a4.z);
      a4.w = fmaf(p, v4[j].w, a4.w);
    }
  }

  const size_t base = (((size_t)(b * HEADS + h)) * NCHUNK + c) * 66;
  part[base + 2 + lq * 4 + 0] = a4.x;
  part[base + 2 + lq * 4 + 1] = a4.y;
  part[base + 2 + lq * 4 + 2] = a4.z;
  part[base + 2 + lq * 4 + 3] = a4.w;
  if (lq == 0) { part[base] = m; part[base + 1] = l; }
}

// ---------------- Kernel C: combine partials ----------------
__global__ __launch_bounds__(64) void attn_combine(
    const float* __restrict__ part, float* __restrict__ attn) {
  const int bh = blockIdx.x;
  const int b = bh >> 4, h = bh & 15;
  const int d = threadIdx.x;
  const float* p0 = part + (size_t)bh * NCHUNK * 66;
  float M = -INFINITY;
#pragma unroll
  for (int c = 0; c < NCHUNK; ++c) M = fmaxf(M, p0[c * 66]);
  float L = 0.f, o = 0.f;
#pragma unroll 8
  for (int c = 0; c < NCHUNK; ++c) {
    const float mc = p0[c * 66];
    if (mc > -INFINITY) {
      const float w = __expf(mc - M);
      L += p0[c * 66 + 1] * w;
      o = fmaf(p0[c * 66 + 2 + d], w, o);
    }
  }
  attn[(size_t)b * DIM + h * HEAD_DIM + d] = o / L;
}

// ---------------- Kernel D: output projection ----------------
__global__ __launch_bounds__(256) void o_proj(
    const float* __restrict__ attn, const float* __restrict__ Wo,
    float* __restrict__ out) {
  __shared__ float tok[BATCH * DIM];
  for (int idx = threadIdx.x; idx < BATCH * DIM; idx += 256)
    tok[idx] = attn[idx];
  __syncthreads();

  const int wave = threadIdx.x >> 6;
  const int lane = threadIdx.x & 63;
  const int i0 = blockIdx.x * 16 + wave * 4;

  float acc[4][16];
#pragma unroll
  for (int ii = 0; ii < 4; ++ii)
#pragma unroll
    for (int b = 0; b < 16; ++b) acc[ii][b] = 0.f;

  for (int t = 0; t < 16; ++t) {
    const int j = t * 64 + lane;
    float tk[16];
#pragma unroll
    for (int b = 0; b < 16; ++b) tk[b] = tok[b * DIM + j];
#pragma unroll
    for (int ii = 0; ii < 4; ++ii) {
      const float w = Wo[(size_t)(i0 + ii) * DIM + j];
#pragma unroll
      for (int b = 0; b < 16; ++b) acc[ii][b] = fmaf(w, tk[b], acc[ii][b]);
    }
  }

#pragma unroll
  for (int ii = 0; ii < 4; ++ii)
#pragma unroll
    for (int b = 0; b < 16; ++b) {
      float v = acc[ii][b];
#pragma unroll
      for (int m = 32; m >= 1; m >>= 1) v += __shfl_xor(v, m);
      if (lane == 0) out[(size_t)b * DIM + i0 + ii] = v;
    }
}

extern "C" void kernel_launch(void* const* d_in, const int* in_sizes, int n_in,
                              void* d_out, int out_size, void* d_ws, size_t ws_size,
                              hipStream_t stream) {
  const float* token = (const float*)d_in[0];
  const float* kc = (const float*)d_in[1];
  const float* vc = (const float*)d_in[2];
  const float* Wq = (const float*)d_in[3];
  const float* Wk = (const float*)d_in[4];
  const float* Wv = (const float*)d_in[5];
  const float* Wo = (const float*)d_in[6];
  const int* pos = (const int*)d_in[7];
  float* out = (float*)d_out;
  float* ws = (float*)d_ws;

  // workspace layout (floats):
  //  [0, 49152)   : q,k,v projections (3 x 16 x 1024)
  //  then         : attention partials 16*16*NCHUNK*66
  //  then         : combined attention output 16 x 1024
  float* qkv = ws;
  float* part = ws + 3 * BATCH * DIM;
  float* attn = part + (size_t)BATCH * HEADS * NCHUNK * 66;

  hipLaunchKernelGGL(qkv_proj, dim3(64, 3), dim3(256), 0, stream,
                     token, Wq, Wk, Wv, qkv);
  hipLaunchKernelGGL(attn_partial, dim3(NCHUNK, BATCH), dim3(256), 0,
                     stream, kc, vc, qkv, pos, part);
  hipLaunchKernelGGL(attn_combine, dim3(BATCH * HEADS), dim3(64), 0, stream,
                     part, attn);
  hipLaunchKernelGGL(o_proj, dim3(64), dim3(256), 0, stream, attn, Wo, out);
  (void)in_sizes; (void)n_in; (void)out_size; (void)ws_size;
}